// Round 3
// baseline (368.014 us; speedup 1.0000x reference)
//
#include <hip/hip_runtime.h>

// Problem constants (fixed by reference): B=128, L=256, F=P=4, IN=1024, H=256, C=7
#define NN 32768        // N = B*L
#define INF 1024
#define HF 256

typedef __bf16 bf16x8 __attribute__((ext_vector_type(8)));
typedef float f32x4 __attribute__((ext_vector_type(4)));
typedef unsigned short u16x8 __attribute__((ext_vector_type(8)));

__device__ __forceinline__ float bf2f(unsigned short u) {
  union { unsigned int i; float f; } v; v.i = ((unsigned int)u) << 16; return v.f;
}
__device__ __forceinline__ unsigned short f2bf(float f) {
  union { float f; unsigned int i; } v; v.f = f;
  unsigned int x = v.i;
  return (unsigned short)((x + 0x7fffu + ((x >> 16) & 1u)) >> 16);  // RNE
}

// async global->LDS, 16B per lane; dest = lds base (wave-uniform) + lane*16
__device__ __forceinline__ void ld_lds16(const unsigned short* g, unsigned short* l) {
  __builtin_amdgcn_global_load_lds(
      (__attribute__((address_space(1))) const unsigned int*)g,
      (__attribute__((address_space(3))) unsigned int*)l, 16, 0, 0);
}

__device__ __forceinline__ f32x4 MF(bf16x8 a, bf16x8 b, f32x4 c) {
  return __builtin_amdgcn_mfma_f32_16x16x32_bf16(a, b, c, 0, 0, 0);
}

// ---- prep:
//  blocks [0,32768):        x fp32 -> bf16 (coalesced float4 copy)  (+loss zero in bid 0)
//  blocks [32768,32768+288): weight repack via 64x64 LDS transpose (coalesced both sides)
// WbigT[n][k] (1024x1024) = [W0|W1|Wroot|Wskip]^T ; WsmT[n][k] (256x512) = [Wgrt;Wrel]^T
__global__ __launch_bounds__(256)
void diagcn_prep(const float* __restrict__ x, const float* __restrict__ Wrgcn,
                 const float* __restrict__ Wroot, const float* __restrict__ Wskip,
                 const float* __restrict__ Wgrt, const float* __restrict__ Wrel,
                 unsigned short* __restrict__ Xbf, unsigned short* __restrict__ WbigT,
                 unsigned short* __restrict__ WsmT, float* __restrict__ loss) {
  int bid = blockIdx.x;
  if (bid < 32768) {
    if (bid == 0 && threadIdx.x == 0) loss[0] = 0.f;
    int idx = bid * 256 + threadIdx.x;   // float4 index into x
    float4 v = ((const float4*)x)[idx];
    ushort4 u; u.x = f2bf(v.x); u.y = f2bf(v.y); u.z = f2bf(v.z); u.w = f2bf(v.w);
    ((ushort4*)Xbf)[idx] = u;
    return;
  }
  __shared__ float tile[64 * 65];
  int tb = bid - 32768;
  const float* src;
  int k0, ncol0;
  unsigned short* dst;
  int ldd, nrow0;
  if (tb < 256) {            // WbigT tiles: tn 0..15, tk 0..15
    int tn = tb >> 4, tk = tb & 15;
    int mat = tn >> 2;
    src = (mat == 0) ? Wrgcn : (mat == 1) ? (Wrgcn + 262144) : (mat == 2) ? Wroot : Wskip;
    k0 = tk * 64; ncol0 = (tn & 3) * 64;
    dst = WbigT; ldd = 1024; nrow0 = tn * 64;
  } else {                   // WsmT tiles: tn 0..3, tk 0..7
    int t2 = tb - 256;
    int tn = t2 >> 3, tk = t2 & 7;
    src = (tk < 4) ? Wgrt : Wrel;
    k0 = (tk & 3) * 64; ncol0 = tn * 64;
    dst = WsmT; ldd = 512; nrow0 = tn * 64;
  }
  int kdst0 = (tb < 256) ? k0 : (((tb - 256) & 7) * 64);
  int c = threadIdx.x & 63, rb = threadIdx.x >> 6;
#pragma unroll
  for (int it = 0; it < 16; ++it) {
    int r = rb + it * 4;
    tile[r * 65 + c] = src[(size_t)(k0 + r) * 256 + ncol0 + c];
  }
  __syncthreads();
  int kk = threadIdx.x & 63;
#pragma unroll
  for (int it = 0; it < 16; ++it) {
    int nn = rb + it * 4;
    dst[(size_t)(nrow0 + nn) * ldd + kdst0 + kk] = f2bf(tile[kk * 65 + nn]);
  }
}

// ---- GEMM1 v4: Y[32768 x 1024] = Xbf @ WbigT^T.
// Faithful port of the verified 256^2 8-phase template (m201-class):
// 256x256 tile, 512 threads (8 waves 2m x 4n -> 128x64/wave), BK=64,
// double-buffered LDS 2 x (A 32KB + B 32KB) = 128 KB.
// Per K-tile: 4 phases, each {ds-read subtile; stage one 16KB half; barrier;
// lgkmcnt(0); setprio(1); 16 MFMA (one C-quadrant); setprio(0); barrier}.
// Stage slots (race-free, hand-verified):
//   p0: (t+1).A-half0 -> buf[(t+1)&1]   (that A region last read tile t-1 p2, drained)
//   p1: (t+1).A-half1 -> buf[(t+1)&1]
//   p2: (t+2).B-half0 -> buf[t&1]       (B of tile t fully drained at p1 lgkm+barrier)
//   p3: (t+2).B-half1 -> buf[t&1]
// One counted vmcnt(4) per tile end (2 halves in flight); never 0 mid-loop.
// B-fragments (8 x bf16x8) live in regs across the tile; A-frags reloaded p0/p2.
// Swizzle: LDS linear; read chunk' = (ks*4+quad) ^ (l15&7); global source chunk
// pre-XORed (lane&7)^(lane>>3)  ->  2 lanes/bank on ds_read_b128, conflict-free.
template<int BUF, bool STGA, bool STGB, int VM>
__device__ __forceinline__ void g1_tile(int t,
    const unsigned short* __restrict__ gA, const unsigned short* __restrict__ gB,
    unsigned short* SH, int w, int aoff0, int aoff1, int boff0, int boff1,
    f32x4 (&acc)[8][4]) {
  const unsigned short* Rb = SH + BUF * 32768;
  bf16x8 av[8], bv[8];
  // ========== phase 0: read A(mi0-3)+B(nj0-1), stage (t+1).A0, MFMA m0 x n0 ==========
#pragma unroll
  for (int mi = 0; mi < 4; ++mi) {
    av[mi * 2 + 0] = *(const bf16x8*)&Rb[aoff0 + mi * 1024];
    av[mi * 2 + 1] = *(const bf16x8*)&Rb[aoff1 + mi * 1024];
  }
#pragma unroll
  for (int nj = 0; nj < 2; ++nj) {
    bv[nj * 2 + 0] = *(const bf16x8*)&Rb[boff0 + nj * 1024];
    bv[nj * 2 + 1] = *(const bf16x8*)&Rb[boff1 + nj * 1024];
  }
  if (STGA) {
    const unsigned short* g = gA + (size_t)(t + 1) * 64;
    unsigned short* d = SH + (BUF ^ 1) * 32768 + w * 512;
    ld_lds16(g, d); ld_lds16(g + 65536, d + 4096);
  }
  asm volatile("s_waitcnt lgkmcnt(8)");
  __builtin_amdgcn_s_barrier();
  asm volatile("s_waitcnt lgkmcnt(0)");
  __builtin_amdgcn_sched_barrier(0);
  __builtin_amdgcn_s_setprio(1);
#pragma unroll
  for (int mi = 0; mi < 4; ++mi)
#pragma unroll
    for (int nj = 0; nj < 2; ++nj) {
      acc[mi][nj] = MF(av[mi * 2 + 0], bv[nj * 2 + 0], acc[mi][nj]);
      acc[mi][nj] = MF(av[mi * 2 + 1], bv[nj * 2 + 1], acc[mi][nj]);
    }
  __builtin_amdgcn_s_setprio(0);
  __builtin_amdgcn_s_barrier();
  // ========== phase 1: read B(nj2-3), stage (t+1).A1, MFMA m0 x n1 ==========
#pragma unroll
  for (int nj = 2; nj < 4; ++nj) {
    bv[nj * 2 + 0] = *(const bf16x8*)&Rb[boff0 + nj * 1024];
    bv[nj * 2 + 1] = *(const bf16x8*)&Rb[boff1 + nj * 1024];
  }
  if (STGA) {
    const unsigned short* g = gA + (size_t)(t + 1) * 64 + 131072;
    unsigned short* d = SH + (BUF ^ 1) * 32768 + 8192 + w * 512;
    ld_lds16(g, d); ld_lds16(g + 65536, d + 4096);
  }
  __builtin_amdgcn_s_barrier();
  asm volatile("s_waitcnt lgkmcnt(0)");
  __builtin_amdgcn_sched_barrier(0);
  __builtin_amdgcn_s_setprio(1);
#pragma unroll
  for (int mi = 0; mi < 4; ++mi)
#pragma unroll
    for (int nj = 2; nj < 4; ++nj) {
      acc[mi][nj] = MF(av[mi * 2 + 0], bv[nj * 2 + 0], acc[mi][nj]);
      acc[mi][nj] = MF(av[mi * 2 + 1], bv[nj * 2 + 1], acc[mi][nj]);
    }
  __builtin_amdgcn_s_setprio(0);
  __builtin_amdgcn_s_barrier();
  // ========== phase 2: read A(mi4-7), stage (t+2).B0, MFMA m1 x n0 ==========
#pragma unroll
  for (int mi = 0; mi < 4; ++mi) {
    av[mi * 2 + 0] = *(const bf16x8*)&Rb[aoff0 + 4096 + mi * 1024];
    av[mi * 2 + 1] = *(const bf16x8*)&Rb[aoff1 + 4096 + mi * 1024];
  }
  if (STGB) {
    const unsigned short* g = gB + (size_t)(t + 2) * 64;
    unsigned short* d = SH + BUF * 32768 + 16384 + w * 512;
    ld_lds16(g, d); ld_lds16(g + 65536, d + 4096);
  }
  __builtin_amdgcn_s_barrier();
  asm volatile("s_waitcnt lgkmcnt(0)");
  __builtin_amdgcn_sched_barrier(0);
  __builtin_amdgcn_s_setprio(1);
#pragma unroll
  for (int mi = 0; mi < 4; ++mi)
#pragma unroll
    for (int nj = 0; nj < 2; ++nj) {
      acc[4 + mi][nj] = MF(av[mi * 2 + 0], bv[nj * 2 + 0], acc[4 + mi][nj]);
      acc[4 + mi][nj] = MF(av[mi * 2 + 1], bv[nj * 2 + 1], acc[4 + mi][nj]);
    }
  __builtin_amdgcn_s_setprio(0);
  __builtin_amdgcn_s_barrier();
  // ========== phase 3: regs only, stage (t+2).B1, MFMA m1 x n1, vmcnt gate ==========
  if (STGB) {
    const unsigned short* g = gB + (size_t)(t + 2) * 64 + 131072;
    unsigned short* d = SH + BUF * 32768 + 24576 + w * 512;
    ld_lds16(g, d); ld_lds16(g + 65536, d + 4096);
  }
  __builtin_amdgcn_s_setprio(1);
#pragma unroll
  for (int mi = 0; mi < 4; ++mi)
#pragma unroll
    for (int nj = 2; nj < 4; ++nj) {
      acc[4 + mi][nj] = MF(av[mi * 2 + 0], bv[nj * 2 + 0], acc[4 + mi][nj]);
      acc[4 + mi][nj] = MF(av[mi * 2 + 1], bv[nj * 2 + 1], acc[4 + mi][nj]);
    }
  __builtin_amdgcn_s_setprio(0);
  if constexpr (VM == 4) asm volatile("s_waitcnt vmcnt(4)" ::: "memory");
  else if constexpr (VM == 0) asm volatile("s_waitcnt vmcnt(0)" ::: "memory");
  if constexpr (VM >= 0) __builtin_amdgcn_s_barrier();
}

__global__ __launch_bounds__(512, 1)
void diagcn_gemm1(const unsigned short* __restrict__ A, const unsigned short* __restrict__ BT,
                  unsigned short* __restrict__ Y) {
  __shared__ unsigned short SH[65536];   // 128 KB: 2 bufs x (A 32KB + B 32KB)
  const int tid = threadIdx.x;
  const int w = tid >> 6, lane = tid & 63;
  const int quad = lane >> 4, l15 = lane & 15;
  const int wm = w >> 2, wn = w & 3;
  const int b = blockIdx.x;
  // XCD-aware bijective swizzle: 512 blocks = 8 XCDs x 64
  const int wg = ((b & 7) << 6) + (b >> 3);
  const int m0 = (wg >> 2) << 8;
  const int n0 = (wg & 3) << 8;
  // read-side swizzled fragment offsets (elements), thread-constant
  const int c0 = ((quad ^ (l15 & 7)) << 3);
  const int c1 = (((4 + quad) ^ (l15 & 7)) << 3);
  const int aoff0 = wm * 8192 + l15 * 64 + c0;
  const int aoff1 = wm * 8192 + l15 * 64 + c1;
  const int boff0 = 16384 + (wn >> 1) * 8192 + ((wn & 1) * 64 + l15) * 64 + c0;
  const int boff1 = 16384 + (wn >> 1) * 8192 + ((wn & 1) * 64 + l15) * 64 + c1;
  // per-thread pre-swizzled global source bases (row = w*8 + lane/8, chunk xor)
  const int ln3 = lane >> 3;
  const int csrc = ((lane & 7) ^ ln3) << 3;
  const unsigned short* gA = A + (size_t)(m0 + w * 8 + ln3) * 1024 + csrc;
  const unsigned short* gB = BT + (size_t)(n0 + w * 8 + ln3) * 1024 + csrc;

  f32x4 acc[8][4] = {};

  // prologue: stage (0).A0,(0).A1,(0).B0,(0).B1,(1).B0,(1).B1  (12 gloads/thread)
  {
    unsigned short* d;
    d = SH + w * 512;                 ld_lds16(gA, d);                    ld_lds16(gA + 65536, d + 4096);
    d = SH + 8192 + w * 512;          ld_lds16(gA + 131072, d);           ld_lds16(gA + 131072 + 65536, d + 4096);
    d = SH + 16384 + w * 512;         ld_lds16(gB, d);                    ld_lds16(gB + 65536, d + 4096);
    d = SH + 24576 + w * 512;         ld_lds16(gB + 131072, d);           ld_lds16(gB + 131072 + 65536, d + 4096);
    d = SH + 32768 + 16384 + w * 512; ld_lds16(gB + 64, d);               ld_lds16(gB + 64 + 65536, d + 4096);
    d = SH + 32768 + 24576 + w * 512; ld_lds16(gB + 64 + 131072, d);      ld_lds16(gB + 64 + 131072 + 65536, d + 4096);
  }
  asm volatile("s_waitcnt vmcnt(4)" ::: "memory");   // tile0's 4 halves landed; (1).B in flight
  __builtin_amdgcn_s_barrier();

#pragma unroll 1
  for (int u = 0; u < 7; ++u) {       // tiles 0..13
    g1_tile<0, true, true, 4>(2 * u,     gA, gB, SH, w, aoff0, aoff1, boff0, boff1, acc);
    g1_tile<1, true, true, 4>(2 * u + 1, gA, gB, SH, w, aoff0, aoff1, boff0, boff1, acc);
  }
  g1_tile<0, true,  false, 0>(14, gA, gB, SH, w, aoff0, aoff1, boff0, boff1, acc);
  g1_tile<1, false, false, -1>(15, gA, gB, SH, w, aoff0, aoff1, boff0, boff1, acc);

  // epilogue: C/D mapping col=lane&15, row=quad*4+r
#pragma unroll
  for (int i = 0; i < 8; ++i)
#pragma unroll
    for (int j = 0; j < 4; ++j) {
      const int row = m0 + wm * 128 + i * 16 + quad * 4;
      const int col = n0 + wn * 64 + j * 16 + l15;
#pragma unroll
      for (int r = 0; r < 4; ++r)
        Y[(size_t)(row + r) * 1024 + col] = f2bf(acc[i][j][r]);
    }
}

// ---- RGCN aggregate, 2 nodes per wave (8 ch/lane, 16B loads), branchless window.
// h_i = Yroot_i + b + sum_r mean_{j in win, rel=r} Y_r[j]; bf16 h -> A2[:,0:256].
__global__ __launch_bounds__(256)
void diagcn_h(const unsigned short* __restrict__ Y, const int* __restrict__ spk,
              const float* __restrict__ brgcn, unsigned short* __restrict__ A2) {
  int b = blockIdx.x;
  int wv = threadIdx.x >> 6, lane = threadIdx.x & 63;
  int half = lane >> 5, li = lane & 31, c0 = li << 3;
  int node = ((b & 7) << 12) + ((b >> 3) << 3) + wv * 2 + half;
  int p = node & 255, dbase = node - p;
  int si = spk[node];
  float a0[8] = {}, a1[8] = {};
  float n0 = 0.f, n1 = 0.f;
#pragma unroll
  for (int d = -4; d <= 4; ++d) {
    int pj = p + d;
    float w = (pj >= 0 && pj < 256) ? 1.f : 0.f;
    int jc = pj < 0 ? 0 : (pj > 255 ? 255 : pj);
    int nj = dbase + jc;
    int rel = si & spk[nj];
    u16x8 v = *(const u16x8*)&Y[(size_t)nj * 1024 + (rel << 8) + c0];
    float w1 = rel ? w : 0.f, w0 = rel ? 0.f : w;
#pragma unroll
    for (int k = 0; k < 8; ++k) {
      float f = bf2f(v[k]);
      a0[k] += f * w0; a1[k] += f * w1;
    }
    n0 += w0; n1 += w1;
  }
  u16x8 vr = *(const u16x8*)&Y[(size_t)node * 1024 + 512 + c0];
  float i0 = 1.f / fmaxf(n0, 1.f), i1 = 1.f / fmaxf(n1, 1.f);
  u16x8 u;
#pragma unroll
  for (int k = 0; k < 8; ++k)
    u[k] = f2bf(bf2f(vr[k]) + brgcn[c0 + k] + a0[k] * i0 + a1[k] * i1);
  *(u16x8*)&A2[(size_t)node * 512 + c0] = u;
}

// ---- GraphConv neighbor sum (aggr=add over window incl. self), 2 nodes/wave.
__global__ __launch_bounds__(256)
void diagcn_neigh(unsigned short* __restrict__ A2) {
  int b = blockIdx.x;
  int wv = threadIdx.x >> 6, lane = threadIdx.x & 63;
  int half = lane >> 5, li = lane & 31, c0 = li << 3;
  int node = ((b & 7) << 12) + ((b >> 3) << 3) + wv * 2 + half;
  int p = node & 255, dbase = node - p;
  float s[8] = {};
#pragma unroll
  for (int d = -4; d <= 4; ++d) {
    int pj = p + d;
    float w = (pj >= 0 && pj < 256) ? 1.f : 0.f;
    int jc = pj < 0 ? 0 : (pj > 255 ? 255 : pj);
    u16x8 v = *(const u16x8*)&A2[(size_t)(dbase + jc) * 512 + c0];
#pragma unroll
    for (int k = 0; k < 8; ++k) s[k] += bf2f(v[k]) * w;
  }
  u16x8 u;
#pragma unroll
  for (int k = 0; k < 8; ++k) u[k] = f2bf(s[k]);
  *(u16x8*)&A2[(size_t)node * 512 + 256 + c0] = u;
}

// ---- GEMM2 + fused epilogue. 64x256 tile (full H per block), K=512.
// z = A2 @ WsmT^T + brel + bskip + Yskip; then out = z @ Wcls + bcls, log-softmax,
// per-row CE loss atomically accumulated. z never touches HBM.
__global__ __launch_bounds__(256)
void diagcn_gemm2(const unsigned short* __restrict__ A, const unsigned short* __restrict__ BT,
                  const unsigned short* __restrict__ Y, const float* __restrict__ Wcls,
                  const float* __restrict__ bcls, const float* __restrict__ brel,
                  const float* __restrict__ bskip, const int* __restrict__ labels,
                  float* __restrict__ out, float* __restrict__ loss) {
  const int K = 512;
  __shared__ unsigned short As[64 * 64];
  __shared__ unsigned short Bs[256 * 64];
  __shared__ float Wc[2312];   // [0,1792) Wcls | [1792,1799) bcls | [1800,2056) brel | [2056,2312) bskip
  for (int i = threadIdx.x; i < 2312; i += 256) {
    float v;
    if (i < 1792) v = Wcls[i];
    else if (i < 1799) v = bcls[i - 1792];
    else if (i < 1800) v = 0.f;
    else if (i < 2056) v = brel[i - 1800];
    else v = bskip[i - 2056];
    Wc[i] = v;
  }
  const int tid = threadIdx.x;
  const int w = tid >> 6, lane = tid & 63;
  const int quad = lane >> 4, l15 = lane & 15;
  const int b = blockIdx.x;
  const int m0 = (((b & 7) << 6) + (b >> 3)) << 6;   // 512 m-tiles of 64 rows
  const int rowg = lane >> 3;
  const int kbsw = (lane & 7) ^ rowg;

  f32x4 acc[16] = {};
  const unsigned short* Abase = A + (size_t)m0 * K + kbsw * 8;
  const unsigned short* Bbase = BT + kbsw * 8;

  for (int k0 = 0; k0 < K; k0 += 64) {
#pragma unroll
    for (int t = 0; t < 2; ++t) {      // A: 8 groups of 8 rows
      int grp = w * 2 + t;
      ld_lds16(Abase + (size_t)(grp * 8 + rowg) * K + k0, &As[grp * 512]);
    }
#pragma unroll
    for (int t = 0; t < 8; ++t) {      // B: 32 groups of 8 rows
      int grp = w * 8 + t;
      ld_lds16(Bbase + (size_t)(grp * 8 + rowg) * K + k0, &Bs[grp * 512]);
    }
    __syncthreads();
#pragma unroll
    for (int ks = 0; ks < 2; ++ks) {
      int kb = ks * 4 + quad;
      int ra = w * 16 + l15;
      bf16x8 av = *(const bf16x8*)&As[ra * 64 + ((kb ^ (ra & 7)) << 3)];
#pragma unroll
      for (int j = 0; j < 16; ++j) {
        int rb2 = j * 16 + l15;
        bf16x8 bv = *(const bf16x8*)&Bs[rb2 * 64 + ((kb ^ (rb2 & 7)) << 3)];
        acc[j] = __builtin_amdgcn_mfma_f32_16x16x32_bf16(av, bv, acc[j], 0, 0, 0);
      }
    }
    __syncthreads();
  }

  // ---- epilogue: bias + skip, classifier partials
  float wsum[4][7] = {};
#pragma unroll
  for (int j = 0; j < 16; ++j) {
    int col = j * 16 + l15;
    float bb = Wc[1800 + col] + Wc[2056 + col];
#pragma unroll
    for (int r = 0; r < 4; ++r) {
      int row = m0 + w * 16 + quad * 4 + r;
      float z = acc[j][r] + bb + bf2f(Y[(size_t)row * 1024 + 768 + col]);
#pragma unroll
      for (int c = 0; c < 7; ++c) wsum[r][c] += z * Wc[col * 7 + c];
    }
  }
  // reduce over the 16 lanes of each quad (cols) -> every lane holds full row dots
#pragma unroll
  for (int o = 1; o < 16; o <<= 1)
#pragma unroll
    for (int r = 0; r < 4; ++r)
#pragma unroll
      for (int c = 0; c < 7; ++c) wsum[r][c] += __shfl_xor(wsum[r][c], o, 64);

  float lsum = 0.f;
#pragma unroll
  for (int r = 0; r < 4; ++r) {
    int row = m0 + w * 16 + quad * 4 + r;
    float o7[7], mx = -1e30f;
#pragma unroll
    for (int c = 0; c < 7; ++c) {
      o7[c] = wsum[r][c] + Wc[1792 + c];
      mx = fmaxf(mx, o7[c]);
    }
    if (l15 < 7) out[(size_t)row * 7 + l15] = o7[l15];
    float s = 0.f;
#pragma unroll
    for (int c = 0; c < 7; ++c) s += expf(o7[c] - mx);
    int lab = labels[row];
    lsum += mx + logf(s) - o7[lab];
  }
  // quad-totals are lane-identical; combine the 4 quads
  lsum += __shfl_xor(lsum, 16, 64);
  lsum += __shfl_xor(lsum, 32, 64);
  if (lane == 0) atomicAdd(loss, lsum * (1.0f / (float)NN));
}

extern "C" void kernel_launch(void* const* d_in, const int* in_sizes, int n_in,
                              void* d_out, int out_size, void* d_ws, size_t ws_size,
                              hipStream_t stream) {
  const float* x      = (const float*)d_in[0];
  const int* speakers = (const int*)d_in[2];
  const int* labels   = (const int*)d_in[3];
  const float* Wrgcn  = (const float*)d_in[6];
  const float* Wroot  = (const float*)d_in[7];
  const float* brgcn  = (const float*)d_in[8];
  const float* Wrel   = (const float*)d_in[9];
  const float* brel   = (const float*)d_in[10];
  const float* Wgrt   = (const float*)d_in[11];
  const float* Wskip  = (const float*)d_in[12];
  const float* bskip  = (const float*)d_in[13];
  const float* Wcls   = (const float*)d_in[14];
  const float* bcls   = (const float*)d_in[15];
  float* out = (float*)d_out;
  float* loss = out + (size_t)NN * 7;

  // workspace layout (bytes)
  const size_t OFF_XBF  = 0;                  // 67,108,864  (bf16 X)
  const size_t OFF_WBIG = 67108864;           //  2,097,152
  const size_t OFF_WSM  = 69206016;           //    262,144
  const size_t OFF_Y    = 69468160;           // 67,108,864  (bf16 [Y0|Y1|Yroot|Yskip])
  const size_t OFF_A2   = 136577024;          // 33,554,432  (bf16 [h|neigh])
  const size_t NEED     = 170131456;
  if (ws_size < NEED) return;

  char* ws = (char*)d_ws;
  unsigned short* Xbf   = (unsigned short*)(ws + OFF_XBF);
  unsigned short* WbigT = (unsigned short*)(ws + OFF_WBIG);
  unsigned short* WsmT  = (unsigned short*)(ws + OFF_WSM);
  unsigned short* Y     = (unsigned short*)(ws + OFF_Y);
  unsigned short* A2    = (unsigned short*)(ws + OFF_A2);

  diagcn_prep<<<dim3(33056), dim3(256), 0, stream>>>(x, Wrgcn, Wroot, Wskip, Wgrt, Wrel,
                                                     Xbf, WbigT, WsmT, loss);
  diagcn_gemm1<<<dim3(512), dim3(512), 0, stream>>>(Xbf, WbigT, Y);
  diagcn_h<<<dim3(NN / 8), dim3(256), 0, stream>>>(Y, speakers, brgcn, A2);
  diagcn_neigh<<<dim3(NN / 8), dim3(256), 0, stream>>>(A2);
  diagcn_gemm2<<<dim3(512), dim3(256), 0, stream>>>(A2, WsmT, Y, Wcls, bcls, brel, bskip,
                                                    labels, out, loss);
}